// Round 1
// baseline (2843.048 us; speedup 1.0000x reference)
//
#include <hip/hip_runtime.h>
#include <math.h>

#define TP    32
#define NTHR  256
#define NPTS  500000
#define NSEG  25000
#define NTILES (NPTS / TP)   // 15625, exact
#define RFF   256
#define DIN   64
#define DMID  128
#define DOUT  64
#define PHI_SCALE 0.08838834764831845f   // sqrt(2/256)

__global__ __launch_bounds__(NTHR, 2)
void dgp_fused(const float* __restrict__ x,
               const float* __restrict__ Om0,
               const float* __restrict__ b0,
               const float* __restrict__ Wm0,
               const float* __restrict__ E0,
               const float* __restrict__ Om1,
               const float* __restrict__ b1,
               const float* __restrict__ Osq,
               const float* __restrict__ Wm1,
               const float* __restrict__ E1,
               const int*   __restrict__ xidx,
               float* __restrict__ sum_wm,
               float* __restrict__ sum_inv)
{
    // padded strides: 68, 132 -> stride%32 = 4, no 2^k bank alignment; rows 16B-aligned
    __shared__ float xs [TP][68];    //  8704 B
    __shared__ float phi[TP][132];   // 16896 B (one 128-wide RFF half)
    __shared__ float m0s[TP][132];   // 16896 B
    __shared__ float v0s[TP][132];   // 16896 B  -> total 59392 B < 64K

    const int t    = threadIdx.x;
    const int lane = t & 63;
    const int w    = t >> 6;          // wave id 0..3
    const int p0   = w * 8;           // this wave owns points p0..p0+7
    const int base = blockIdx.x * TP;
    const int j0   = lane * 2;        // 2 output cols per lane (covers 0..127)

    // ---- load x tile: 32 pts x 64 dims, coalesced float4 ----
    {
        const int p = t >> 3;
        const int c = (t & 7) * 8;
        const float* g = x + (size_t)(base + p) * DIN + c;
        float4 a = *reinterpret_cast<const float4*>(g);
        float4 b = *reinterpret_cast<const float4*>(g + 4);
        *reinterpret_cast<float4*>(&xs[p][c])     = a;
        *reinterpret_cast<float4*>(&xs[p][c + 4]) = b;
    }
    __syncthreads();

    float accm[8][2] = {{0.f}}, accv[8][2] = {{0.f}};

    #pragma unroll
    for (int h = 0; h < 2; ++h) {
        // ---- GEMM1: z0[p][h*128+j0..] = xs @ Om0 ----
        float az[8][2] = {{0.f}};
        {
            const float* B = Om0 + h * 128 + j0;
            for (int k = 0; k < DIN; k += 4) {
                float4 xv[8];
                #pragma unroll
                for (int i = 0; i < 8; ++i)
                    xv[i] = *reinterpret_cast<const float4*>(&xs[p0 + i][k]);
                #pragma unroll
                for (int kk = 0; kk < 4; ++kk) {
                    float2 wv = *reinterpret_cast<const float2*>(B + (k + kk) * RFF);
                    #pragma unroll
                    for (int i = 0; i < 8; ++i) {
                        const float xk = reinterpret_cast<const float*>(&xv[i])[kk];
                        az[i][0] = fmaf(xk, wv.x, az[i][0]);
                        az[i][1] = fmaf(xk, wv.y, az[i][1]);
                    }
                }
            }
        }
        // phi0 = scale * cos(z + b0)
        {
            float2 bb = *reinterpret_cast<const float2*>(b0 + h * 128 + j0);
            #pragma unroll
            for (int i = 0; i < 8; ++i) {
                float pa = PHI_SCALE * __cosf(az[i][0] + bb.x);
                float pb = PHI_SCALE * __cosf(az[i][1] + bb.y);
                *reinterpret_cast<float2*>(&phi[p0 + i][j0]) = make_float2(pa, pb);
            }
        }
        __syncthreads();

        // ---- GEMM2: m0 += phi @ Wm0, v0 += phi^2 @ exp(Wlv0) (accumulate across halves) ----
        {
            const float* Wb = Wm0 + (size_t)h * 128 * DMID + j0;
            const float* Eb = E0  + (size_t)h * 128 * DMID + j0;
            for (int k = 0; k < 128; k += 4) {
                float4 pv[8];
                #pragma unroll
                for (int i = 0; i < 8; ++i)
                    pv[i] = *reinterpret_cast<const float4*>(&phi[p0 + i][k]);
                #pragma unroll
                for (int kk = 0; kk < 4; ++kk) {
                    float2 wm = *reinterpret_cast<const float2*>(Wb + (k + kk) * DMID);
                    float2 we = *reinterpret_cast<const float2*>(Eb + (k + kk) * DMID);
                    #pragma unroll
                    for (int i = 0; i < 8; ++i) {
                        const float pp = reinterpret_cast<const float*>(&pv[i])[kk];
                        const float p2 = pp * pp;
                        accm[i][0] = fmaf(pp, wm.x, accm[i][0]);
                        accm[i][1] = fmaf(pp, wm.y, accm[i][1]);
                        accv[i][0] = fmaf(p2, we.x, accv[i][0]);
                        accv[i][1] = fmaf(p2, we.y, accv[i][1]);
                    }
                }
            }
        }
        __syncthreads();   // phi free for next half
    }

    // ---- stash m0, v0 (lane*2 covers all 128 dims) ----
    #pragma unroll
    for (int i = 0; i < 8; ++i) {
        *reinterpret_cast<float2*>(&m0s[p0 + i][j0]) = make_float2(accm[i][0], accm[i][1]);
        *reinterpret_cast<float2*>(&v0s[p0 + i][j0]) = make_float2(accv[i][0], accv[i][1]);
    }
    __syncthreads();

    float m1a[8] = {0.f}, v1a[8] = {0.f};

    #pragma unroll
    for (int h = 0; h < 2; ++h) {
        // ---- GEMM3: z1 = m0 @ Om1, damp = v0 @ Om1^2 ----
        float az[8][2] = {{0.f}}, ad[8][2] = {{0.f}};
        {
            const float* Bz = Om1 + h * 128 + j0;
            const float* Bd = Osq + h * 128 + j0;
            for (int k = 0; k < DMID; k += 4) {
                float4 mv[8], vv[8];
                #pragma unroll
                for (int i = 0; i < 8; ++i) {
                    mv[i] = *reinterpret_cast<const float4*>(&m0s[p0 + i][k]);
                    vv[i] = *reinterpret_cast<const float4*>(&v0s[p0 + i][k]);
                }
                #pragma unroll
                for (int kk = 0; kk < 4; ++kk) {
                    float2 wz = *reinterpret_cast<const float2*>(Bz + (k + kk) * RFF);
                    float2 wd = *reinterpret_cast<const float2*>(Bd + (k + kk) * RFF);
                    #pragma unroll
                    for (int i = 0; i < 8; ++i) {
                        const float mk = reinterpret_cast<const float*>(&mv[i])[kk];
                        const float vk = reinterpret_cast<const float*>(&vv[i])[kk];
                        az[i][0] = fmaf(mk, wz.x, az[i][0]);
                        az[i][1] = fmaf(mk, wz.y, az[i][1]);
                        ad[i][0] = fmaf(vk, wd.x, ad[i][0]);
                        ad[i][1] = fmaf(vk, wd.y, ad[i][1]);
                    }
                }
            }
        }
        // phi1 = scale * cos(z1 + b1) * exp(-0.5*damp)   (phi last read before a barrier)
        {
            float2 bb = *reinterpret_cast<const float2*>(b1 + h * 128 + j0);
            #pragma unroll
            for (int i = 0; i < 8; ++i) {
                float pa = PHI_SCALE * __cosf(az[i][0] + bb.x) * __expf(-0.5f * ad[i][0]);
                float pb = PHI_SCALE * __cosf(az[i][1] + bb.y) * __expf(-0.5f * ad[i][1]);
                *reinterpret_cast<float2*>(&phi[p0 + i][j0]) = make_float2(pa, pb);
            }
        }
        __syncthreads();

        // ---- GEMM4: m1 += phi @ Wm1, v1 += phi^2 @ exp(Wlv1); one dim per lane ----
        {
            const float* Wb = Wm1 + (size_t)h * 128 * DOUT + lane;
            const float* Eb = E1  + (size_t)h * 128 * DOUT + lane;
            for (int k = 0; k < 128; k += 4) {
                float4 pv[8];
                #pragma unroll
                for (int i = 0; i < 8; ++i)
                    pv[i] = *reinterpret_cast<const float4*>(&phi[p0 + i][k]);
                #pragma unroll
                for (int kk = 0; kk < 4; ++kk) {
                    const float wm = Wb[(k + kk) * DOUT];
                    const float we = Eb[(k + kk) * DOUT];
                    #pragma unroll
                    for (int i = 0; i < 8; ++i) {
                        const float pp = reinterpret_cast<const float*>(&pv[i])[kk];
                        m1a[i] = fmaf(pp, wm, m1a[i]);
                        v1a[i] = fmaf(pp * pp, we, v1a[i]);
                    }
                }
            }
        }
        __syncthreads();
    }

    // ---- normalize rows (64 dims across the wave) + segment atomics ----
    #pragma unroll
    for (int i = 0; i < 8; ++i) {
        float s = m1a[i] * m1a[i];
        #pragma unroll
        for (int off = 32; off > 0; off >>= 1)
            s += __shfl_xor(s, off, 64);
        const float scale = 1.0f / fmaxf(sqrtf(s), 1e-12f);
        const float mn  = m1a[i] * scale;
        const float inv = 1.0f / v1a[i];
        const int   seg = xidx[base + p0 + i];
        atomicAdd(&sum_inv[(size_t)seg * DOUT + lane], inv);
        atomicAdd(&sum_wm [(size_t)seg * DOUT + lane], inv * mn);
    }
}

// precompute exp(Wlv0) [256x128], exp(Wlv1) [256x64], Omega1^2 [128x256]
__global__ void dgp_prep(const float* __restrict__ Wlv0,
                         const float* __restrict__ Wlv1,
                         const float* __restrict__ Om1,
                         float* __restrict__ E0,
                         float* __restrict__ E1,
                         float* __restrict__ Osq)
{
    const int i = blockIdx.x * blockDim.x + threadIdx.x;   // 0..32767
    if (i < RFF * DMID) E0[i] = expf(Wlv0[i]);
    if (i < RFF * DOUT) E1[i] = expf(Wlv1[i]);
    if (i < DMID * RFF) { float v = Om1[i]; Osq[i] = v * v; }
}

// in-place: out0 slot holds sum_wm, out1 slot holds sum_inv
__global__ void dgp_finalize(float* __restrict__ out)
{
    const int i = blockIdx.x * blockDim.x + threadIdx.x;
    if (i < NSEG * DOUT) {
        const float si = out[NSEG * DOUT + i];   // sum_inv
        const float sw = out[i];                 // sum_wm
        const float ev = 1.0f / si;              // embed_vars (inf if empty, matches ref)
        out[i]              = ev * sw;
        out[NSEG * DOUT + i] = ev;
    }
}

extern "C" void kernel_launch(void* const* d_in, const int* in_sizes, int n_in,
                              void* d_out, int out_size, void* d_ws, size_t ws_size,
                              hipStream_t stream)
{
    const float* x    = (const float*)d_in[0];
    const float* Om0  = (const float*)d_in[1];
    const float* b0   = (const float*)d_in[2];
    const float* Wm0  = (const float*)d_in[3];
    const float* Wlv0 = (const float*)d_in[4];
    const float* Om1  = (const float*)d_in[5];
    const float* b1   = (const float*)d_in[6];
    const float* Wm1  = (const float*)d_in[7];
    const float* Wlv1 = (const float*)d_in[8];
    const int*   xidx = (const int*)d_in[9];

    float* out = (float*)d_out;
    float* ws  = (float*)d_ws;
    float* E0  = ws;                 // 32768 floats
    float* E1  = ws + 32768;         // 16384 floats
    float* Osq = ws + 49152;         // 32768 floats

    // zero accumulators (atomics target d_out directly); deterministic per replay
    hipMemsetAsync(d_out, 0, (size_t)out_size * sizeof(float), stream);

    dgp_prep<<<128, 256, 0, stream>>>(Wlv0, Wlv1, Om1, E0, E1, Osq);

    float* sum_wm  = out;                    // -> becomes output 0
    float* sum_inv = out + NSEG * DOUT;      // -> becomes output 1 (embed_vars)
    dgp_fused<<<NTILES, NTHR, 0, stream>>>(x, Om0, b0, Wm0, E0, Om1, b1, Osq,
                                           Wm1, E1, xidx, sum_wm, sum_inv);

    dgp_finalize<<<(NSEG * DOUT + 255) / 256, 256, 0, stream>>>(out);
}

// Round 2
// 641.557 us; speedup vs baseline: 4.4315x; 4.4315x over previous
//
#include <hip/hip_runtime.h>
#include <math.h>

#define NSEG 25000
#define NPTS 500000

typedef __attribute__((ext_vector_type(8))) short v8s;
typedef __attribute__((ext_vector_type(4))) float v4f;

#define MF(a,b,c) __builtin_amdgcn_mfma_f32_16x16x32_bf16(a,b,c,0,0,0)

// ---- d_ws byte offsets (weight planes in B-fragment order, bf16) ----
// frag order: tile T = (k>>5)*NT + (n>>4); lane = ((k>>3)&3)*16 + (n&15); j = k&7
// element offset = T*512 + lane*8 + j   (so each lane loads 16B contiguous per tile)
#define W1H 0        // Om0 hi   64x256  (32KB)
#define W1L 32768    // Om0 lo
#define W2H 65536    // Wm0 hi   256x128 (64KB)
#define W2L 131072   // Wm0 lo
#define W2E 196608   // exp(Wlv0) hi
#define W3H 262144   // Om1 hi   128x256
#define W3L 327680   // Om1 lo
#define W3S 393216   // Om1^2 hi
#define W4H 458752   // Wm1 hi   256x64  (32KB)
#define W4E 491520   // exp(Wlv1) hi
// total 512KB in d_ws

// ---- LDS arena (per block, 63KB => 2 blocks/CU) ----
// A-fragment line layout: per (ktile, row): [hi x32 elems (64B)][lo x32 (64B)][pad 16] = 144B
// hi-only planes: [hi x32 (64B)][pad 16] = 80B
#define XS   0       // x tile: 3m * (2kt*16rows*144) = 13824
#define P0   13824   // phi0 quarter (K=64): 3m * (2kt*16*144) = 13824
#define P0S  27648   // phi0^2 quarter: 3m * (2kt*16*80) = 7680
#define M0   0       // m0: 3m * (4kt*16*144) = 27648   (reuses XS+P0 after G2)
#define V0   27648   // v0: 3m * (4kt*16*80) = 15360    (reuses P0S+)
#define P1   43008   // phi1 quarter: 13824
#define P1S  56832   // phi1^2 quarter: 7680
#define NRM  43008   // 48 pts * 32B, reuses P1 after last G4 barrier
#define LDSZ 64512

__device__ __forceinline__ ushort bf16_rne(float f) {
    uint u = __builtin_bit_cast(uint, f);
    u += 0x7fffu + ((u >> 16) & 1u);
    return (ushort)(u >> 16);
}
__device__ __forceinline__ float bf16f(ushort h) {
    uint u = ((uint)h) << 16;
    return __builtin_bit_cast(float, u);
}

// ---------- weight prep: split fp32 -> bf16 hi/lo in fragment order ----------
__global__ void dgp_prep(const float* __restrict__ Om0, const float* __restrict__ Wm0,
                         const float* __restrict__ Wlv0, const float* __restrict__ Om1,
                         const float* __restrict__ Wm1, const float* __restrict__ Wlv1,
                         char* __restrict__ ws)
{
    const int idx = blockIdx.x * 256 + threadIdx.x;   // 0..32767 exactly
    // plane 1: Om0 K=64 N=256 (16384 el)
    if (idx < 16384) {
        int k = idx >> 8, n = idx & 255;
        int off = ((k >> 5) * 16 + (n >> 4)) * 512 + (((k >> 3) & 3) * 16 + (n & 15)) * 8 + (k & 7);
        float v = Om0[idx];
        ushort hi = bf16_rne(v), lo = bf16_rne(v - bf16f(hi));
        ((ushort*)(ws + W1H))[off] = hi;
        ((ushort*)(ws + W1L))[off] = lo;
    }
    // plane 2: Wm0 / exp(Wlv0) K=256 N=128 (32768 el)
    {
        int k = idx >> 7, n = idx & 127;
        int off = ((k >> 5) * 8 + (n >> 4)) * 512 + (((k >> 3) & 3) * 16 + (n & 15)) * 8 + (k & 7);
        float v = Wm0[idx];
        ushort hi = bf16_rne(v), lo = bf16_rne(v - bf16f(hi));
        ((ushort*)(ws + W2H))[off] = hi;
        ((ushort*)(ws + W2L))[off] = lo;
        ((ushort*)(ws + W2E))[off] = bf16_rne(expf(Wlv0[idx]));
    }
    // plane 3: Om1 / Om1^2 K=128 N=256 (32768 el)
    {
        int k = idx >> 8, n = idx & 255;
        int off = ((k >> 5) * 16 + (n >> 4)) * 512 + (((k >> 3) & 3) * 16 + (n & 15)) * 8 + (k & 7);
        float v = Om1[idx];
        ushort hi = bf16_rne(v), lo = bf16_rne(v - bf16f(hi));
        ((ushort*)(ws + W3H))[off] = hi;
        ((ushort*)(ws + W3L))[off] = lo;
        ((ushort*)(ws + W3S))[off] = bf16_rne(v * v);
    }
    // plane 4: Wm1 / exp(Wlv1) K=256 N=64 (16384 el)
    if (idx < 16384) {
        int k = idx >> 6, n = idx & 63;
        int off = ((k >> 5) * 4 + (n >> 4)) * 512 + (((k >> 3) & 3) * 16 + (n & 15)) * 8 + (k & 7);
        ((ushort*)(ws + W4H))[off] = bf16_rne(Wm1[idx]);
        ((ushort*)(ws + W4E))[off] = bf16_rne(expf(Wlv1[idx]));
    }
}

// ---------- fused main kernel: 48 points/block, 4 waves N-split ----------
__global__ __launch_bounds__(256, 2)
void dgp_main(const float* __restrict__ x, const int* __restrict__ xidx,
              const float* __restrict__ b0, const float* __restrict__ b1,
              const char* __restrict__ ws,
              float* __restrict__ sum_wm, float* __restrict__ sum_inv)
{
    __shared__ __align__(16) char lds[LDSZ];
    const int t = threadIdx.x;
    const int l = t & 63;
    const int w = t >> 6;            // wave 0..3
    const int r16 = l & 15;
    const int g = l >> 4;            // lane quad 0..3
    const size_t base = (size_t)blockIdx.x * 48;
    const int valid = min(48, (int)(NPTS - (int)base));

    // ---- stage x tile: 48x64 fp32 -> hi/lo bf16 A-fragment layout ----
    #pragma unroll
    for (int it = 0; it < 3; ++it) {
        int idx = t + it * 256;              // 0..767
        int p = idx >> 4, c4 = (idx & 15) << 2;
        int pc = min(p, valid - 1);
        const float4 xv = *(const float4*)(x + (base + pc) * 64 + c4);
        char* ln = lds + XS + (p >> 4) * 4608 + (c4 >> 5) * 2304 + (p & 15) * 144;
        int e0 = c4 & 31;
        ushort h0 = bf16_rne(xv.x), h1 = bf16_rne(xv.y), h2 = bf16_rne(xv.z), h3 = bf16_rne(xv.w);
        ushort q0 = bf16_rne(xv.x - bf16f(h0)), q1 = bf16_rne(xv.y - bf16f(h1));
        ushort q2 = bf16_rne(xv.z - bf16f(h2)), q3 = bf16_rne(xv.w - bf16f(h3));
        unsigned long long hp = (unsigned long long)h0 | ((unsigned long long)h1 << 16) |
                                ((unsigned long long)h2 << 32) | ((unsigned long long)h3 << 48);
        unsigned long long lp = (unsigned long long)q0 | ((unsigned long long)q1 << 16) |
                                ((unsigned long long)q2 << 32) | ((unsigned long long)q3 << 48);
        *(unsigned long long*)(ln + e0 * 2) = hp;
        *(unsigned long long*)(ln + 64 + e0 * 2) = lp;
    }
    __syncthreads();

    const v4f zf = {0.f, 0.f, 0.f, 0.f};
    v4f am[3][2], av[3][2];
    #pragma unroll
    for (int m = 0; m < 3; ++m) { am[m][0] = zf; am[m][1] = zf; av[m][0] = zf; av[m][1] = zf; }

    // ================= layer 0: G1 (x@Om0 -> phi0) + G2 (phi0@Wm0 / phi0^2@E0) =================
    for (int q = 0; q < 4; ++q) {
        const int ntg = (q << 2) + w;        // global n-tile 0..15
        // G1 B-frags (Om0 hi/lo, 2 K-tiles)
        const v8s b1h0 = *(const v8s*)(ws + W1H + (size_t)((0 * 16 + ntg) * 64 + l) * 16);
        const v8s b1l0 = *(const v8s*)(ws + W1L + (size_t)((0 * 16 + ntg) * 64 + l) * 16);
        const v8s b1h1 = *(const v8s*)(ws + W1H + (size_t)((1 * 16 + ntg) * 64 + l) * 16);
        const v8s b1l1 = *(const v8s*)(ws + W1L + (size_t)((1 * 16 + ntg) * 64 + l) * 16);
        v4f az[3] = {zf, zf, zf};
        #pragma unroll
        for (int m = 0; m < 3; ++m) {
            const char* lab = lds + XS + m * 4608 + r16 * 144 + g * 16;
            v8s ah0 = *(const v8s*)(lab);
            v8s al0 = *(const v8s*)(lab + 64);
            v8s ah1 = *(const v8s*)(lab + 2304);
            v8s al1 = *(const v8s*)(lab + 2304 + 64);
            v4f a = az[m];
            a = MF(ah0, b1h0, a); a = MF(ah0, b1l0, a); a = MF(al0, b1h0, a);
            a = MF(ah1, b1h1, a); a = MF(ah1, b1l1, a); a = MF(al1, b1h1, a);
            az[m] = a;
        }
        // elementwise: phi0 = s*cos(z+b0); write hi/lo/sq quarter (this wave's 16 k-cols)
        {
            const float bb = b0[ntg * 16 + r16];
            char* lnb = lds + P0 + (w >> 1) * 2304;
            char* lsb = lds + P0S + (w >> 1) * 1280;
            const int e = ((w & 1) << 4) + r16;
            #pragma unroll
            for (int m = 0; m < 3; ++m) {
                #pragma unroll
                for (int qi = 0; qi < 4; ++qi) {
                    const int row = (g << 2) + qi;
                    float ph = 0.08838834764831845f * __cosf(az[m][qi] + bb);
                    ushort hi = bf16_rne(ph);
                    ushort lo = bf16_rne(ph - bf16f(hi));
                    *(short*)(lnb + m * 4608 + row * 144 + e * 2) = (short)hi;
                    *(short*)(lnb + m * 4608 + row * 144 + 64 + e * 2) = (short)lo;
                    *(short*)(lsb + m * 2560 + row * 80 + e * 2) = (short)bf16_rne(ph * ph);
                }
            }
        }
        __syncthreads();
        // G2 quarter: nt = 2w, 2w+1; accumulate m0/v0 in regs
        #pragma unroll
        for (int kt2 = 0; kt2 < 2; ++kt2) {
            const int ktg = (q << 1) + kt2;
            const v8s b2h0 = *(const v8s*)(ws + W2H + (size_t)((ktg * 8 + 2 * w) * 64 + l) * 16);
            const v8s b2l0 = *(const v8s*)(ws + W2L + (size_t)((ktg * 8 + 2 * w) * 64 + l) * 16);
            const v8s b2e0 = *(const v8s*)(ws + W2E + (size_t)((ktg * 8 + 2 * w) * 64 + l) * 16);
            const v8s b2h1 = *(const v8s*)(ws + W2H + (size_t)((ktg * 8 + 2 * w + 1) * 64 + l) * 16);
            const v8s b2l1 = *(const v8s*)(ws + W2L + (size_t)((ktg * 8 + 2 * w + 1) * 64 + l) * 16);
            const v8s b2e1 = *(const v8s*)(ws + W2E + (size_t)((ktg * 8 + 2 * w + 1) * 64 + l) * 16);
            #pragma unroll
            for (int m = 0; m < 3; ++m) {
                const char* lab = lds + P0 + m * 4608 + kt2 * 2304 + r16 * 144 + g * 16;
                v8s ah = *(const v8s*)(lab);
                v8s al = *(const v8s*)(lab + 64);
                v8s as = *(const v8s*)(lds + P0S + m * 2560 + kt2 * 1280 + r16 * 80 + g * 16);
                am[m][0] = MF(al, b2h0, MF(ah, b2l0, MF(ah, b2h0, am[m][0])));
                am[m][1] = MF(al, b2h1, MF(ah, b2l1, MF(ah, b2h1, am[m][1])));
                av[m][0] = MF(as, b2e0, av[m][0]);
                av[m][1] = MF(as, b2e1, av[m][1]);
            }
        }
        __syncthreads();   // protect phi0 buffers for next quarter
    }

    // ---- stash m0 (hi/lo) and v0 (hi) into LDS A-fragment layout ----
    #pragma unroll
    for (int m = 0; m < 3; ++m) {
        #pragma unroll
        for (int nx = 0; nx < 2; ++nx) {
            const int e = (nx << 4) + r16;   // k-col within this wave's K-tile (kt = w)
            #pragma unroll
            for (int qi = 0; qi < 4; ++qi) {
                const int row = (g << 2) + qi;
                float mv = am[m][nx][qi];
                ushort hi = bf16_rne(mv);
                ushort lo = bf16_rne(mv - bf16f(hi));
                char* ln = lds + M0 + m * 9216 + w * 2304 + row * 144;
                *(short*)(ln + e * 2) = (short)hi;
                *(short*)(ln + 64 + e * 2) = (short)lo;
                *(short*)(lds + V0 + m * 5120 + w * 1280 + row * 80 + e * 2) = (short)bf16_rne(av[m][nx][qi]);
            }
        }
    }
    __syncthreads();

    // ================= layer 1: G3 (m0@Om1, v0@Om1^2 -> phi1) + G4 =================
    v4f m1[3] = {zf, zf, zf}, v1[3] = {zf, zf, zf};
    for (int ch = 0; ch < 4; ++ch) {
        const int ntg = (ch << 2) + w;
        v4f az[3] = {zf, zf, zf}, ad[3] = {zf, zf, zf};
        #pragma unroll
        for (int kt = 0; kt < 4; ++kt) {
            const v8s bh = *(const v8s*)(ws + W3H + (size_t)((kt * 16 + ntg) * 64 + l) * 16);
            const v8s bl = *(const v8s*)(ws + W3L + (size_t)((kt * 16 + ntg) * 64 + l) * 16);
            const v8s bs = *(const v8s*)(ws + W3S + (size_t)((kt * 16 + ntg) * 64 + l) * 16);
            #pragma unroll
            for (int m = 0; m < 3; ++m) {
                const char* lab = lds + M0 + m * 9216 + kt * 2304 + r16 * 144 + g * 16;
                v8s ah = *(const v8s*)(lab);
                v8s al = *(const v8s*)(lab + 64);
                v8s avv = *(const v8s*)(lds + V0 + m * 5120 + kt * 1280 + r16 * 80 + g * 16);
                az[m] = MF(al, bh, MF(ah, bl, MF(ah, bh, az[m])));
                ad[m] = MF(avv, bs, ad[m]);
            }
        }
        // phi1 = s*cos(z1+b1)*exp(-0.5*damp)
        {
            const float bb = b1[ntg * 16 + r16];
            char* lnb = lds + P1 + (w >> 1) * 2304;
            char* lsb = lds + P1S + (w >> 1) * 1280;
            const int e = ((w & 1) << 4) + r16;
            #pragma unroll
            for (int m = 0; m < 3; ++m) {
                #pragma unroll
                for (int qi = 0; qi < 4; ++qi) {
                    const int row = (g << 2) + qi;
                    float ph = 0.08838834764831845f * __cosf(az[m][qi] + bb) * __expf(-0.5f * ad[m][qi]);
                    ushort hi = bf16_rne(ph);
                    ushort lo = bf16_rne(ph - bf16f(hi));
                    *(short*)(lnb + m * 4608 + row * 144 + e * 2) = (short)hi;
                    *(short*)(lnb + m * 4608 + row * 144 + 64 + e * 2) = (short)lo;
                    *(short*)(lsb + m * 2560 + row * 80 + e * 2) = (short)bf16_rne(ph * ph);
                }
            }
        }
        __syncthreads();
        // G4: single-term bf16 (precision budget allows); wave owns n-tile w
        #pragma unroll
        for (int kt2 = 0; kt2 < 2; ++kt2) {
            const int kt4 = (ch << 1) + kt2;
            const v8s bh = *(const v8s*)(ws + W4H + (size_t)((kt4 * 4 + w) * 64 + l) * 16);
            const v8s be = *(const v8s*)(ws + W4E + (size_t)((kt4 * 4 + w) * 64 + l) * 16);
            #pragma unroll
            for (int m = 0; m < 3; ++m) {
                v8s ah = *(const v8s*)(lds + P1 + m * 4608 + kt2 * 2304 + r16 * 144 + g * 16);
                v8s as = *(const v8s*)(lds + P1S + m * 2560 + kt2 * 1280 + r16 * 80 + g * 16);
                m1[m] = MF(ah, bh, m1[m]);
                v1[m] = MF(as, be, v1[m]);
            }
        }
        __syncthreads();   // protect phi1 buffers for next chunk (and NRM reuse)
    }

    // ================= epilogue: normalize + inverse-variance atomics =================
    #pragma unroll
    for (int m = 0; m < 3; ++m) {
        #pragma unroll
        for (int qi = 0; qi < 4; ++qi) {
            float s = m1[m][qi] * m1[m][qi];
            s += __shfl_xor(s, 1); s += __shfl_xor(s, 2);
            s += __shfl_xor(s, 4); s += __shfl_xor(s, 8);
            if (r16 == 0)
                *(float*)(lds + NRM + ((m << 4) + (g << 2) + qi) * 32 + w * 4) = s;
        }
    }
    __syncthreads();
    const int c = (w << 4) + r16;    // output col 0..63
    #pragma unroll
    for (int m = 0; m < 3; ++m) {
        #pragma unroll
        for (int qi = 0; qi < 4; ++qi) {
            const int p = (m << 4) + (g << 2) + qi;
            const float4 sv = *(const float4*)(lds + NRM + p * 32);
            const float s = sv.x + sv.y + sv.z + sv.w;
            const float inv_n = 1.0f / fmaxf(sqrtf(s), 1e-12f);
            const float iv = 1.0f / v1[m][qi];
            if (p < valid) {
                const int seg = xidx[base + p];
                atomicAdd(&sum_inv[(size_t)seg * 64 + c], iv);
                atomicAdd(&sum_wm[(size_t)seg * 64 + c], iv * m1[m][qi] * inv_n);
            }
        }
    }
}

// in-place: out0 slot holds sum_wm, out1 slot holds sum_inv
__global__ void dgp_finalize(float* __restrict__ out)
{
    const int i = blockIdx.x * blockDim.x + threadIdx.x;
    if (i < NSEG * 64) {
        const float si = out[NSEG * 64 + i];
        const float sw = out[i];
        const float ev = 1.0f / si;
        out[i] = ev * sw;
        out[NSEG * 64 + i] = ev;
    }
}

extern "C" void kernel_launch(void* const* d_in, const int* in_sizes, int n_in,
                              void* d_out, int out_size, void* d_ws, size_t ws_size,
                              hipStream_t stream)
{
    const float* x    = (const float*)d_in[0];
    const float* Om0  = (const float*)d_in[1];
    const float* b0   = (const float*)d_in[2];
    const float* Wm0  = (const float*)d_in[3];
    const float* Wlv0 = (const float*)d_in[4];
    const float* Om1  = (const float*)d_in[5];
    const float* b1   = (const float*)d_in[6];
    const float* Wm1  = (const float*)d_in[7];
    const float* Wlv1 = (const float*)d_in[8];
    const int*   xidx = (const int*)d_in[9];

    float* out = (float*)d_out;

    // zero atomic accumulators (graph-capture-safe)
    hipMemsetAsync(d_out, 0, (size_t)out_size * sizeof(float), stream);

    // weights -> bf16 hi/lo fragment planes in d_ws (512KB)
    dgp_prep<<<128, 256, 0, stream>>>(Om0, Wm0, Wlv0, Om1, Wm1, Wlv1, (char*)d_ws);

    float* sum_wm  = out;               // -> output 0
    float* sum_inv = out + NSEG * 64;   // -> output 1 (embed_vars)
    const int nblk = (NPTS + 47) / 48;  // 10417
    dgp_main<<<nblk, 256, 0, stream>>>(x, xidx, b0, b1, (const char*)d_ws, sum_wm, sum_inv);

    dgp_finalize<<<(NSEG * 64 + 255) / 256, 256, 0, stream>>>(out);
}